// Round 1
// baseline (35810.675 us; speedup 1.0000x reference)
//
#include <hip/hip_runtime.h>
#include <math.h>

// ---------------- problem constants ----------------
#define NTOK 8192            // B*T
#define DM   512
#define HID  1024            // per-direction hidden
#define G3H  3072            // 3*HID
#define GOUT 2048            // 2*HID (bidir concat)
#define FFND 2048
#define NEXP 8

// ---------------- ws layout (bytes) ----------------
#define XG_OFF    0ULL                 // fp32 [8192][6144] = 201326592
#define HG_OFF    0ULL                 // alias (after GRU): fp32 [16384][2048] = 134217728
#define OG_OFF    134217728ULL         // fp32 [16384][512] = 33554432 (inside xg region)
#define FLAT_OFF  201326592ULL         // fp32 [8192][2048] = 67108864
#define HBUF_OFF  268435456ULL         // fp32 [2][2][8192] = 131072
#define FLAGS_OFF 268566528ULL         // int [2][128] -> 1024
#define IMETA_OFF 268567552ULL         // int meta, 4096
#define FMETA_OFF 268571648ULL         // float meta, 4096
#define TKIDX_OFF 268575744ULL         // int [16384]
#define TKW_OFF   268641280ULL         // float [16384]
#define PAIRT_OFF 268706816ULL         // int [16384]
#define PAIRW_OFF 268772352ULL         // float [16384]
#define SLOT_OFF  268837888ULL         // int [16384]
// imeta ints: [0..8) counts, [8..16) cursor, [16..25) offs, [25] Ttot,
//             [32..168) tileExp, [168..304) tileStart
// fmeta floats: [0..8) sumP, [8] zacc

// =====================================================================
// K0: zero hbuf + flags + meta (region [HBUF_OFF, TKIDX_OFF) = 35072 floats)
// =====================================================================
__global__ void k0_init(float* p) {
    int i = blockIdx.x * 256 + threadIdx.x;
    if (i < 35072) p[i] = 0.f;
}

// =====================================================================
// K1: fp32 SGEMM  C[M=8192][N=6144] = A[8192][512] * B[6144][512]^T + bias[N]
// (A = x, B = Wih rows, bias = bih flat). 128x128 tile, BK=16, 256 thr.
// =====================================================================
__global__ __launch_bounds__(256, 2) void k1_sgemm_bt(
    const float* __restrict__ A, const float* __restrict__ B,
    const float* __restrict__ bias, float* __restrict__ C) {
    __shared__ float As[16 * 132];
    __shared__ float Bs[16 * 132];
    const int tid = threadIdx.x;
    const int m0 = blockIdx.y * 128;
    const int n0 = blockIdx.x * 128;
    const int tx = tid & 15, ty = tid >> 4;
    const int arow = tid >> 2, ac4 = (tid & 3) * 4;
    float acc[8][8];
#pragma unroll
    for (int i = 0; i < 8; ++i)
#pragma unroll
        for (int j = 0; j < 8; ++j) acc[i][j] = 0.f;

    for (int k0 = 0; k0 < 512; k0 += 16) {
        __syncthreads();
#pragma unroll
        for (int r = 0; r < 2; ++r) {
            int row = r * 64 + arow;
            float4 va = *(const float4*)(A + (size_t)(m0 + row) * 512 + k0 + ac4);
            As[(ac4 + 0) * 132 + row] = va.x;
            As[(ac4 + 1) * 132 + row] = va.y;
            As[(ac4 + 2) * 132 + row] = va.z;
            As[(ac4 + 3) * 132 + row] = va.w;
            float4 vb = *(const float4*)(B + (size_t)(n0 + row) * 512 + k0 + ac4);
            Bs[(ac4 + 0) * 132 + row] = vb.x;
            Bs[(ac4 + 1) * 132 + row] = vb.y;
            Bs[(ac4 + 2) * 132 + row] = vb.z;
            Bs[(ac4 + 3) * 132 + row] = vb.w;
        }
        __syncthreads();
#pragma unroll
        for (int k = 0; k < 16; ++k) {
            float4 a0 = *(const float4*)&As[k * 132 + ty * 8];
            float4 a1 = *(const float4*)&As[k * 132 + ty * 8 + 4];
            float4 b0 = *(const float4*)&Bs[k * 132 + tx * 8];
            float4 b1 = *(const float4*)&Bs[k * 132 + tx * 8 + 4];
            float av[8] = {a0.x, a0.y, a0.z, a0.w, a1.x, a1.y, a1.z, a1.w};
            float bv[8] = {b0.x, b0.y, b0.z, b0.w, b1.x, b1.y, b1.z, b1.w};
#pragma unroll
            for (int i = 0; i < 8; ++i)
#pragma unroll
                for (int j = 0; j < 8; ++j) acc[i][j] = fmaf(av[i], bv[j], acc[i][j]);
        }
    }
    float4 c0 = *(const float4*)(bias + n0 + tx * 8);
    float4 c1 = *(const float4*)(bias + n0 + tx * 8 + 4);
    float bb[8] = {c0.x, c0.y, c0.z, c0.w, c1.x, c1.y, c1.z, c1.w};
#pragma unroll
    for (int i = 0; i < 8; ++i) {
        float* op = C + (size_t)(m0 + ty * 8 + i) * 6144 + n0 + tx * 8;
        float4 o0 = make_float4(acc[i][0] + bb[0], acc[i][1] + bb[1],
                                acc[i][2] + bb[2], acc[i][3] + bb[3]);
        float4 o1 = make_float4(acc[i][4] + bb[4], acc[i][5] + bb[5],
                                acc[i][6] + bb[6], acc[i][7] + bb[7]);
        *(float4*)op = o0;
        *(float4*)(op + 4) = o1;
    }
}

// =====================================================================
// K2: persistent bidirectional GRU. 256 WGs (dir = bid>>7, 8 units each).
// Whh fp32 in LDS; h double-buffered in global; flag barrier per step.
// =====================================================================
__global__ __launch_bounds__(256) void k2_gru(
    const float* __restrict__ Whh, const float* __restrict__ bhh,
    const float* __restrict__ xg, float* __restrict__ flat,
    float* __restrict__ hbuf, int* __restrict__ flags) {
    __shared__ float Wl[1024 * 24];   // [k][r]  r = g*8+u
    __shared__ float red[32 * 200];   // [kc][r*8+b] stride 200
    __shared__ float s2[192];
    const int tid = threadIdx.x;
    const int dir = blockIdx.x >> 7;
    const int wg = blockIdx.x & 127;
    const int j0 = wg * 8;
    const float* W0 = Whh + (size_t)dir * G3H * HID;
    for (int idx = tid; idx < 24 * 1024; idx += 256) {
        int r = idx >> 10, k = idx & 1023;
        int g = r >> 3, u = r & 7;
        Wl[k * 24 + r] = W0[(size_t)(g * 1024 + j0 + u) * 1024 + k];
    }
    const int lane = tid & 63;
    const int b = tid & 7;
    const int kc = tid >> 3;      // 0..31
    const int kb = kc * 32;
    float* hb = hbuf + dir * 16384;
    int* fl = flags + dir * 128;
    float bhh_r = 0.f;
    if (tid < 192) {
        int r = tid >> 3;
        int g = r >> 3, u = r & 7;
        bhh_r = bhh[dir * G3H + g * 1024 + j0 + u];
    }
    const float4* wbase[6];
    int qrow[6];
#pragma unroll
    for (int m = 0; m < 6; ++m) {
        int q = (m + kc) % 6;
        qrow[m] = q * 4;
        wbase[m] = (const float4*)&Wl[kb * 24 + q * 4];
    }
    __syncthreads();

    for (int s = 1; s <= 1024; ++s) {
        const int te = dir ? (1024 - s) : (s - 1);
        float xr = 0.f, xz = 0.f, xn = 0.f;
        if (tid < 64) {
            int u = tid >> 3, bb2 = tid & 7;
            const float* xp = xg + (size_t)(bb2 * 1024 + te) * 6144 + dir * G3H + j0 + u;
            xr = xp[0];
            xz = xp[1024];
            xn = xp[2048];
        }
        if (s > 1) {
            const int c0 = s - 1;
            int it = 0;
            for (;;) {
                int f0 = __hip_atomic_load(fl + lane, __ATOMIC_RELAXED, __HIP_MEMORY_SCOPE_AGENT);
                int f1 = __hip_atomic_load(fl + 64 + lane, __ATOMIC_RELAXED, __HIP_MEMORY_SCOPE_AGENT);
                if (__all((f0 >= c0) && (f1 >= c0))) break;
                if (++it > (1 << 24)) break;   // safety: never hang the GPU
                __builtin_amdgcn_s_sleep(2);
            }
            __threadfence();   // acquire: invalidate stale L1/L2
        }
        const float* hp = hb + ((s - 1) & 1) * 8192;  // [k][b]
        float hreg[32];
#pragma unroll
        for (int i = 0; i < 32; ++i) hreg[i] = hp[(kb + i) * 8 + b];
        float hpg = 0.f;
        if (tid < 64) hpg = hp[(j0 + (tid >> 3)) * 8 + (tid & 7)];

        float4 acc[6];
#pragma unroll
        for (int m = 0; m < 6; ++m) acc[m] = make_float4(0.f, 0.f, 0.f, 0.f);
#pragma unroll
        for (int i = 0; i < 32; ++i) {
            float hv = hreg[i];
#pragma unroll
            for (int m = 0; m < 6; ++m) {
                float4 wv = wbase[m][i * 6];
                acc[m].x = fmaf(wv.x, hv, acc[m].x);
                acc[m].y = fmaf(wv.y, hv, acc[m].y);
                acc[m].z = fmaf(wv.z, hv, acc[m].z);
                acc[m].w = fmaf(wv.w, hv, acc[m].w);
            }
        }
#pragma unroll
        for (int m = 0; m < 6; ++m) {
            float* rp = &red[kc * 200 + qrow[m] * 8 + b];
            rp[0] = acc[m].x;
            rp[8] = acc[m].y;
            rp[16] = acc[m].z;
            rp[24] = acc[m].w;
        }
        __syncthreads();
        if (tid < 192) {
            float sum = 0.f;
#pragma unroll
            for (int kk = 0; kk < 32; ++kk) sum += red[kk * 200 + tid];
            s2[tid] = sum + bhh_r;
        }
        __syncthreads();
        if (tid < 64) {
            int u = tid >> 3, bb2 = tid & 7;
            float hr = s2[u * 8 + bb2];
            float hz = s2[(8 + u) * 8 + bb2];
            float hn = s2[(16 + u) * 8 + bb2];
            float rg = 1.f / (1.f + expf(-(xr + hr)));
            float zg = 1.f / (1.f + expf(-(xz + hz)));
            float ng = tanhf(xn + rg * hn);
            float hnew = (1.f - zg) * ng + zg * hpg;
            hb[(s & 1) * 8192 + (j0 + u) * 8 + bb2] = hnew;
            float lr = hnew > 0.f ? hnew : 0.01f * hnew;
            flat[(size_t)(bb2 * 1024 + te) * 2048 + dir * 1024 + j0 + u] = lr;
        }
        __syncthreads();
        if (tid == 0) {
            __threadfence();  // release: flush h slice before flag
            __hip_atomic_store(fl + wg, s, __ATOMIC_RELEASE, __HIP_MEMORY_SCOPE_AGENT);
        }
    }
}

// =====================================================================
// K3: gating — fp32 logits from fp32 flat, softmax, top-2, aux partials
// =====================================================================
__global__ __launch_bounds__(256) void k3_gate(
    const float* __restrict__ flat, const float* __restrict__ gate_W,
    const float* __restrict__ gate_b,
    int* __restrict__ tk_idx, float* __restrict__ tk_w,
    int* __restrict__ counts, float* __restrict__ fmeta) {
    __shared__ float gw[8 * 2048];
    __shared__ float bP[9];
    __shared__ int bC[8];
    const int tid = threadIdx.x;
    for (int i = tid; i < 8 * 2048; i += 256) gw[i] = gate_W[i];
    if (tid < 9) bP[tid] = 0.f;
    if (tid < 8) bC[tid] = 0;
    __syncthreads();
    const int lane = tid & 63, w = tid >> 6;
    const int tbase = blockIdx.x * 16 + w * 4;
    for (int j = 0; j < 4; ++j) {
        int t = tbase + j;
        const float* fr = flat + (size_t)t * 2048;
        float a[8];
#pragma unroll
        for (int e = 0; e < 8; ++e) a[e] = 0.f;
        for (int i = 0; i < 32; ++i) {
            float v = fr[i * 64 + lane];
#pragma unroll
            for (int e = 0; e < 8; ++e) a[e] = fmaf(v, gw[e * 2048 + i * 64 + lane], a[e]);
        }
#pragma unroll
        for (int e = 0; e < 8; ++e) {
#pragma unroll
            for (int off = 32; off > 0; off >>= 1) a[e] += __shfl_down(a[e], off);
        }
        if (lane == 0) {
            float lg[8];
#pragma unroll
            for (int e = 0; e < 8; ++e) lg[e] = a[e] + gate_b[e];
            float m = lg[0];
#pragma unroll
            for (int e = 1; e < 8; ++e) m = fmaxf(m, lg[e]);
            float sc[8], ssum = 0.f;
#pragma unroll
            for (int e = 0; e < 8; ++e) { sc[e] = expf(lg[e] - m); ssum += sc[e]; }
            float inv = 1.f / ssum;
#pragma unroll
            for (int e = 0; e < 8; ++e) sc[e] *= inv;
            float lse = m + logf(ssum);
            int i1 = 0; float s1 = sc[0];
#pragma unroll
            for (int e = 1; e < 8; ++e) if (sc[e] > s1) { s1 = sc[e]; i1 = e; }
            int i2 = (i1 == 0) ? 1 : 0; float s2v = sc[i2];
#pragma unroll
            for (int e = 0; e < 8; ++e) if (e != i1 && sc[e] > s2v) { s2v = sc[e]; i2 = e; }
            float wsum = s1 + s2v;
            tk_idx[2 * t] = i1; tk_idx[2 * t + 1] = i2;
            tk_w[2 * t] = s1 / wsum; tk_w[2 * t + 1] = s2v / wsum;
            atomicAdd(&bC[i1], 1);
            atomicAdd(&bC[i2], 1);
#pragma unroll
            for (int e = 0; e < 8; ++e) atomicAdd(&bP[e], sc[e]);
            atomicAdd(&bP[8], lse * lse);
        }
    }
    __syncthreads();
    if (tid < 8) {
        atomicAdd(&counts[tid], bC[tid]);
        atomicAdd(&fmeta[tid], bP[tid]);
    }
    if (tid == 8) atomicAdd(&fmeta[8], bP[8]);
}

// =====================================================================
// K4: schedule (offsets, tile table) + aux loss
// =====================================================================
__global__ void k4_sched(int* im, float* fm, float* aux_out) {
    int tid = threadIdx.x;
    if (tid < 136) { im[32 + tid] = -1; im[168 + tid] = 0; }
    __syncthreads();
    if (tid == 0) {
        int off = 0;
        for (int e = 0; e < 8; ++e) { im[16 + e] = off; im[8 + e] = off; off += im[e]; }
        im[24] = off;
        int T = 0;
        for (int e = 0; e < 8; ++e) {
            int c = im[e], o = im[16 + e];
            for (int i = 0; i < c; i += 128) { im[32 + T] = e; im[168 + T] = o + i; ++T; }
        }
        im[25] = T;
        float fP = 0.f;
        for (int e = 0; e < 8; ++e) fP += ((float)im[e] / 8192.f) * (fm[e] / 8192.f);
        *aux_out = 0.01f * 8.f * fP + 0.001f * (fm[8] / 8192.f);
    }
}

// =====================================================================
// K5: scatter tokens into per-expert pair lists (block-aggregated atomics)
// =====================================================================
__global__ __launch_bounds__(256) void k5_scatter(
    const int* __restrict__ tk_idx, const float* __restrict__ tk_w,
    int* __restrict__ im, int* __restrict__ pair_t,
    float* __restrict__ pair_w, int* __restrict__ slot) {
    __shared__ int cnt[8], base[8];
    const int tid = threadIdx.x;
    if (tid < 8) cnt[tid] = 0;
    __syncthreads();
    const int t = blockIdx.x * 256 + tid;
    const int e0 = tk_idx[2 * t], e1 = tk_idx[2 * t + 1];
    const int p0 = atomicAdd(&cnt[e0], 1);
    const int p1 = atomicAdd(&cnt[e1], 1);
    __syncthreads();
    if (tid < 8) base[tid] = atomicAdd(&im[8 + tid], cnt[tid]);
    __syncthreads();
    const int q0 = base[e0] + p0, q1 = base[e1] + p1;
    pair_t[q0] = t; pair_w[q0] = tk_w[2 * t];     slot[2 * t] = q0;
    pair_t[q1] = t; pair_w[q1] = tk_w[2 * t + 1]; slot[2 * t + 1] = q1;
}

// =====================================================================
// K6: grouped FFN1 — Hg[p][f] = gelu(flat[token(p)] @ W1[e] + b1[e])
// =====================================================================
__global__ __launch_bounds__(256, 2) void k6_ffn1(
    const float* __restrict__ flat, const float* __restrict__ W1,
    const float* __restrict__ b1, const int* __restrict__ im,
    const int* __restrict__ pair_t, float* __restrict__ Hg) {
    const int rt = blockIdx.x % 136;
    const int nt = blockIdx.x / 136;
    const int e = im[32 + rt];
    if (e < 0) return;
    const int pStart = im[168 + rt];
    const int pEnd = im[16 + e + 1];
    __shared__ float As[16 * 132];
    __shared__ float Bs[16 * 132];
    const int tid = threadIdx.x;
    const int tx = tid & 15, ty = tid >> 4;
    const int n0 = nt * 128;
    const float* Bb = W1 + (size_t)e * 2048 * 2048;
    const int arow = tid >> 2, ac4 = (tid & 3) * 4;
    const int bk = tid >> 4, bn = (tid & 15) * 8;
    int r0 = pStart + arow;       if (r0 > pEnd - 1) r0 = pEnd - 1;
    int r1 = pStart + 64 + arow;  if (r1 > pEnd - 1) r1 = pEnd - 1;
    const float* arp0 = flat + (size_t)pair_t[r0] * 2048;
    const float* arp1 = flat + (size_t)pair_t[r1] * 2048;
    float acc[8][8];
#pragma unroll
    for (int i = 0; i < 8; ++i)
#pragma unroll
        for (int j = 0; j < 8; ++j) acc[i][j] = 0.f;

    for (int k0 = 0; k0 < 2048; k0 += 16) {
        __syncthreads();
        {
            float4 va = *(const float4*)(arp0 + k0 + ac4);
            As[(ac4 + 0) * 132 + arow] = va.x;
            As[(ac4 + 1) * 132 + arow] = va.y;
            As[(ac4 + 2) * 132 + arow] = va.z;
            As[(ac4 + 3) * 132 + arow] = va.w;
            float4 vb = *(const float4*)(arp1 + k0 + ac4);
            As[(ac4 + 0) * 132 + 64 + arow] = vb.x;
            As[(ac4 + 1) * 132 + 64 + arow] = vb.y;
            As[(ac4 + 2) * 132 + 64 + arow] = vb.z;
            As[(ac4 + 3) * 132 + 64 + arow] = vb.w;
            float4 w0 = *(const float4*)(Bb + (size_t)(k0 + bk) * 2048 + n0 + bn);
            float4 w1 = *(const float4*)(Bb + (size_t)(k0 + bk) * 2048 + n0 + bn + 4);
            *(float4*)&Bs[bk * 132 + bn] = w0;
            *(float4*)&Bs[bk * 132 + bn + 4] = w1;
        }
        __syncthreads();
#pragma unroll
        for (int k = 0; k < 16; ++k) {
            float4 a0 = *(const float4*)&As[k * 132 + ty * 8];
            float4 a1 = *(const float4*)&As[k * 132 + ty * 8 + 4];
            float4 b0 = *(const float4*)&Bs[k * 132 + tx * 8];
            float4 b1v = *(const float4*)&Bs[k * 132 + tx * 8 + 4];
            float av[8] = {a0.x, a0.y, a0.z, a0.w, a1.x, a1.y, a1.z, a1.w};
            float bv[8] = {b0.x, b0.y, b0.z, b0.w, b1v.x, b1v.y, b1v.z, b1v.w};
#pragma unroll
            for (int i = 0; i < 8; ++i)
#pragma unroll
                for (int j = 0; j < 8; ++j) acc[i][j] = fmaf(av[i], bv[j], acc[i][j]);
        }
    }
    float4 c0 = *(const float4*)(b1 + (size_t)e * 2048 + n0 + tx * 8);
    float4 c1 = *(const float4*)(b1 + (size_t)e * 2048 + n0 + tx * 8 + 4);
    float bb[8] = {c0.x, c0.y, c0.z, c0.w, c1.x, c1.y, c1.z, c1.w};
#pragma unroll
    for (int i = 0; i < 8; ++i) {
        int p = pStart + ty * 8 + i;
        if (p < pEnd) {
            float* op = Hg + (size_t)p * 2048 + n0 + tx * 8;
            float o[8];
#pragma unroll
            for (int j = 0; j < 8; ++j) {
                float xv = acc[i][j] + bb[j];
                o[j] = 0.5f * xv * (1.f + erff(xv * 0.70710678118654752f));
            }
            *(float4*)op = make_float4(o[0], o[1], o[2], o[3]);
            *(float4*)(op + 4) = make_float4(o[4], o[5], o[6], o[7]);
        }
    }
}

// =====================================================================
// K7: grouped FFN2 — Og[p][d] = Hg[p] @ W2[e] + b2[e]
// =====================================================================
__global__ __launch_bounds__(256, 2) void k7_ffn2(
    const float* __restrict__ Hg, const float* __restrict__ W2,
    const float* __restrict__ b2, const int* __restrict__ im,
    float* __restrict__ Og) {
    const int rt = blockIdx.x % 136;
    const int nt = blockIdx.x / 136;
    const int e = im[32 + rt];
    if (e < 0) return;
    const int pStart = im[168 + rt];
    const int pEnd = im[16 + e + 1];
    __shared__ float As[16 * 132];
    __shared__ float Bs[16 * 132];
    const int tid = threadIdx.x;
    const int tx = tid & 15, ty = tid >> 4;
    const int n0 = nt * 128;
    const float* Bb = W2 + (size_t)e * 2048 * 512;
    const int arow = tid >> 2, ac4 = (tid & 3) * 4;
    const int bk = tid >> 4, bn = (tid & 15) * 8;
    int r0 = pStart + arow;       if (r0 > pEnd - 1) r0 = pEnd - 1;
    int r1 = pStart + 64 + arow;  if (r1 > pEnd - 1) r1 = pEnd - 1;
    const float* arp0 = Hg + (size_t)r0 * 2048;
    const float* arp1 = Hg + (size_t)r1 * 2048;
    float acc[8][8];
#pragma unroll
    for (int i = 0; i < 8; ++i)
#pragma unroll
        for (int j = 0; j < 8; ++j) acc[i][j] = 0.f;

    for (int k0 = 0; k0 < 2048; k0 += 16) {
        __syncthreads();
        {
            float4 va = *(const float4*)(arp0 + k0 + ac4);
            As[(ac4 + 0) * 132 + arow] = va.x;
            As[(ac4 + 1) * 132 + arow] = va.y;
            As[(ac4 + 2) * 132 + arow] = va.z;
            As[(ac4 + 3) * 132 + arow] = va.w;
            float4 vb = *(const float4*)(arp1 + k0 + ac4);
            As[(ac4 + 0) * 132 + 64 + arow] = vb.x;
            As[(ac4 + 1) * 132 + 64 + arow] = vb.y;
            As[(ac4 + 2) * 132 + 64 + arow] = vb.z;
            As[(ac4 + 3) * 132 + 64 + arow] = vb.w;
            float4 w0 = *(const float4*)(Bb + (size_t)(k0 + bk) * 512 + n0 + bn);
            float4 w1 = *(const float4*)(Bb + (size_t)(k0 + bk) * 512 + n0 + bn + 4);
            *(float4*)&Bs[bk * 132 + bn] = w0;
            *(float4*)&Bs[bk * 132 + bn + 4] = w1;
        }
        __syncthreads();
#pragma unroll
        for (int k = 0; k < 16; ++k) {
            float4 a0 = *(const float4*)&As[k * 132 + ty * 8];
            float4 a1 = *(const float4*)&As[k * 132 + ty * 8 + 4];
            float4 b0 = *(const float4*)&Bs[k * 132 + tx * 8];
            float4 b1v = *(const float4*)&Bs[k * 132 + tx * 8 + 4];
            float av[8] = {a0.x, a0.y, a0.z, a0.w, a1.x, a1.y, a1.z, a1.w};
            float bv[8] = {b0.x, b0.y, b0.z, b0.w, b1v.x, b1v.y, b1v.z, b1v.w};
#pragma unroll
            for (int i = 0; i < 8; ++i)
#pragma unroll
                for (int j = 0; j < 8; ++j) acc[i][j] = fmaf(av[i], bv[j], acc[i][j]);
        }
    }
    float4 c0 = *(const float4*)(b2 + (size_t)e * 512 + n0 + tx * 8);
    float4 c1 = *(const float4*)(b2 + (size_t)e * 512 + n0 + tx * 8 + 4);
    float bb[8] = {c0.x, c0.y, c0.z, c0.w, c1.x, c1.y, c1.z, c1.w};
#pragma unroll
    for (int i = 0; i < 8; ++i) {
        int p = pStart + ty * 8 + i;
        if (p < pEnd) {
            float* op = Og + (size_t)p * 512 + n0 + tx * 8;
            *(float4*)op = make_float4(acc[i][0] + bb[0], acc[i][1] + bb[1],
                                       acc[i][2] + bb[2], acc[i][3] + bb[3]);
            *(float4*)(op + 4) = make_float4(acc[i][4] + bb[4], acc[i][5] + bb[5],
                                             acc[i][6] + bb[6], acc[i][7] + bb[7]);
        }
    }
}

// =====================================================================
// K8: combine — out[t] = w0*Og[s0] + w1*Og[s1]
// =====================================================================
__global__ __launch_bounds__(256) void k8_comb(
    const float* __restrict__ Og, const int* __restrict__ slot,
    const float* __restrict__ pw, float* __restrict__ out) {
    const int i4 = blockIdx.x * 256 + threadIdx.x;   // < 1048576
    const int t = i4 >> 7;
    const int d = (i4 & 127) << 2;
    const int s0 = slot[2 * t], s1 = slot[2 * t + 1];
    const float w0 = pw[s0], w1 = pw[s1];
    float4 a = *(const float4*)(Og + (size_t)s0 * 512 + d);
    float4 b = *(const float4*)(Og + (size_t)s1 * 512 + d);
    float4 o = make_float4(w0 * a.x + w1 * b.x, w0 * a.y + w1 * b.y,
                           w0 * a.z + w1 * b.z, w0 * a.w + w1 * b.w);
    *(float4*)(out + (size_t)t * 512 + d) = o;
}

// =====================================================================
extern "C" void kernel_launch(void* const* d_in, const int* in_sizes, int n_in,
                              void* d_out, int out_size, void* d_ws, size_t ws_size,
                              hipStream_t stream) {
    (void)in_sizes; (void)n_in; (void)out_size; (void)ws_size;
    const float* x   = (const float*)d_in[0];
    const float* Wih = (const float*)d_in[1];
    const float* Whh = (const float*)d_in[2];
    const float* bih = (const float*)d_in[3];
    const float* bhh = (const float*)d_in[4];
    const float* gW  = (const float*)d_in[5];
    const float* gb  = (const float*)d_in[6];
    const float* W1  = (const float*)d_in[7];
    const float* b1  = (const float*)d_in[8];
    const float* W2  = (const float*)d_in[9];
    const float* b2  = (const float*)d_in[10];
    float* out = (float*)d_out;
    char* ws = (char*)d_ws;
    float* xg    = (float*)(ws + XG_OFF);
    float* Hg    = (float*)(ws + HG_OFF);
    float* Og    = (float*)(ws + OG_OFF);
    float* flat  = (float*)(ws + FLAT_OFF);
    float* hbuf  = (float*)(ws + HBUF_OFF);
    int*   flags = (int*)(ws + FLAGS_OFF);
    int*   im    = (int*)(ws + IMETA_OFF);
    float* fm    = (float*)(ws + FMETA_OFF);
    int*   tki   = (int*)(ws + TKIDX_OFF);
    float* tkw   = (float*)(ws + TKW_OFF);
    int*   prt   = (int*)(ws + PAIRT_OFF);
    float* prw   = (float*)(ws + PAIRW_OFF);
    int*   slt   = (int*)(ws + SLOT_OFF);

    hipLaunchKernelGGL(k0_init, dim3(138), dim3(256), 0, stream, (float*)(ws + HBUF_OFF));
    hipLaunchKernelGGL(k1_sgemm_bt, dim3(48, 64), dim3(256), 0, stream, x, Wih, bih, xg);
    hipLaunchKernelGGL(k2_gru, dim3(256), dim3(256), 0, stream, Whh, bhh, xg, flat, hbuf, flags);
    hipLaunchKernelGGL(k3_gate, dim3(512), dim3(256), 0, stream, flat, gW, gb, tki, tkw, im, fm);
    hipLaunchKernelGGL(k4_sched, dim3(1), dim3(256), 0, stream, im, fm, out + 4194304);
    hipLaunchKernelGGL(k5_scatter, dim3(32), dim3(256), 0, stream, tki, tkw, im, prt, prw, slt);
    hipLaunchKernelGGL(k6_ffn1, dim3(136 * 16), dim3(256), 0, stream, flat, W1, b1, im, prt, Hg);
    hipLaunchKernelGGL(k7_ffn2, dim3(136 * 4), dim3(256), 0, stream, Hg, W2, b2, im, Og);
    hipLaunchKernelGGL(k8_comb, dim3(4096), dim3(256), 0, stream, Og, slt, prw, out);
}

// Round 2
// 16135.252 us; speedup vs baseline: 2.2194x; 2.2194x over previous
//
#include <hip/hip_runtime.h>
#include <math.h>

// ---------------- problem constants ----------------
#define NTOK 8192            // B*T
#define DM   512
#define HID  1024            // per-direction hidden
#define G3H  3072            // 3*HID
#define GOUT 2048            // 2*HID (bidir concat)
#define FFND 2048
#define NEXP 8

// ---------------- ws layout (bytes) ----------------
#define XG_OFF    0ULL                 // fp32 [8192][6144] = 201326592
#define HG_OFF    0ULL                 // alias (after GRU): fp32 [16384][2048] = 134217728
#define OG_OFF    134217728ULL         // fp32 [16384][512] = 33554432 (inside xg region)
#define FLAT_OFF  201326592ULL         // fp32 [8192][2048] = 67108864
#define HBUF_OFF  268435456ULL         // fp32 [2][2][8192] = 131072
#define FLAGS_OFF 268566528ULL         // int: monotonic counters cnt[dir] at [dir*32]
#define IMETA_OFF 268567552ULL         // int meta, 4096
#define FMETA_OFF 268571648ULL         // float meta, 4096
#define TKIDX_OFF 268575744ULL         // int [16384]
#define TKW_OFF   268641280ULL         // float [16384]
#define PAIRT_OFF 268706816ULL         // int [16384]
#define PAIRW_OFF 268772352ULL         // float [16384]
#define SLOT_OFF  268837888ULL         // int [16384]
// imeta ints: [0..8) counts, [8..16) cursor, [16..25) offs, [25] Ttot,
//             [32..168) tileExp, [168..304) tileStart
// fmeta floats: [0..8) sumP, [8] zacc

// =====================================================================
// K0: zero hbuf + counters + meta (region [HBUF_OFF, TKIDX_OFF) = 35072 floats)
// =====================================================================
__global__ void k0_init(float* p) {
    int i = blockIdx.x * 256 + threadIdx.x;
    if (i < 35072) p[i] = 0.f;
}

// =====================================================================
// K1: fp32 SGEMM  C[M=8192][N=6144] = A[8192][512] * B[6144][512]^T + bias[N]
// =====================================================================
__global__ __launch_bounds__(256, 2) void k1_sgemm_bt(
    const float* __restrict__ A, const float* __restrict__ B,
    const float* __restrict__ bias, float* __restrict__ C) {
    __shared__ float As[16 * 132];
    __shared__ float Bs[16 * 132];
    const int tid = threadIdx.x;
    const int m0 = blockIdx.y * 128;
    const int n0 = blockIdx.x * 128;
    const int tx = tid & 15, ty = tid >> 4;
    const int arow = tid >> 2, ac4 = (tid & 3) * 4;
    float acc[8][8];
#pragma unroll
    for (int i = 0; i < 8; ++i)
#pragma unroll
        for (int j = 0; j < 8; ++j) acc[i][j] = 0.f;

    for (int k0 = 0; k0 < 512; k0 += 16) {
        __syncthreads();
#pragma unroll
        for (int r = 0; r < 2; ++r) {
            int row = r * 64 + arow;
            float4 va = *(const float4*)(A + (size_t)(m0 + row) * 512 + k0 + ac4);
            As[(ac4 + 0) * 132 + row] = va.x;
            As[(ac4 + 1) * 132 + row] = va.y;
            As[(ac4 + 2) * 132 + row] = va.z;
            As[(ac4 + 3) * 132 + row] = va.w;
            float4 vb = *(const float4*)(B + (size_t)(n0 + row) * 512 + k0 + ac4);
            Bs[(ac4 + 0) * 132 + row] = vb.x;
            Bs[(ac4 + 1) * 132 + row] = vb.y;
            Bs[(ac4 + 2) * 132 + row] = vb.z;
            Bs[(ac4 + 3) * 132 + row] = vb.w;
        }
        __syncthreads();
#pragma unroll
        for (int k = 0; k < 16; ++k) {
            float4 a0 = *(const float4*)&As[k * 132 + ty * 8];
            float4 a1 = *(const float4*)&As[k * 132 + ty * 8 + 4];
            float4 b0 = *(const float4*)&Bs[k * 132 + tx * 8];
            float4 b1 = *(const float4*)&Bs[k * 132 + tx * 8 + 4];
            float av[8] = {a0.x, a0.y, a0.z, a0.w, a1.x, a1.y, a1.z, a1.w};
            float bv[8] = {b0.x, b0.y, b0.z, b0.w, b1.x, b1.y, b1.z, b1.w};
#pragma unroll
            for (int i = 0; i < 8; ++i)
#pragma unroll
                for (int j = 0; j < 8; ++j) acc[i][j] = fmaf(av[i], bv[j], acc[i][j]);
        }
    }
    float4 c0 = *(const float4*)(bias + n0 + tx * 8);
    float4 c1 = *(const float4*)(bias + n0 + tx * 8 + 4);
    float bb[8] = {c0.x, c0.y, c0.z, c0.w, c1.x, c1.y, c1.z, c1.w};
#pragma unroll
    for (int i = 0; i < 8; ++i) {
        float* op = C + (size_t)(m0 + ty * 8 + i) * 6144 + n0 + tx * 8;
        float4 o0 = make_float4(acc[i][0] + bb[0], acc[i][1] + bb[1],
                                acc[i][2] + bb[2], acc[i][3] + bb[3]);
        float4 o1 = make_float4(acc[i][4] + bb[4], acc[i][5] + bb[5],
                                acc[i][6] + bb[6], acc[i][7] + bb[7]);
        *(float4*)op = o0;
        *(float4*)(op + 4) = o1;
    }
}

// =====================================================================
// K2: persistent bidirectional GRU. 256 WGs (dir = bid>>7, 8 units each).
// Whh fp32 in LDS; h double-buffered in global, accessed with fine-grained
// coherent (sc0/sc1) atomics -> NO bulk L2 writeback/invalidate fences.
// Arrival via one monotonic counter per dir (relaxed agent atomicAdd).
// =====================================================================
__global__ __launch_bounds__(256) void k2_gru(
    const float* __restrict__ Whh, const float* __restrict__ bhh,
    const float* __restrict__ xg, float* __restrict__ flat,
    float* __restrict__ hbuf, int* __restrict__ flags) {
    __shared__ float Wl[1024 * 24];   // [k][r]  r = g*8+u
    __shared__ float red[32 * 200];   // [kc][r*8+b] stride 200
    __shared__ float s2[192];
    const int tid = threadIdx.x;
    const int dir = blockIdx.x >> 7;
    const int wg = blockIdx.x & 127;
    const int j0 = wg * 8;
    const float* W0 = Whh + (size_t)dir * G3H * HID;
    for (int idx = tid; idx < 24 * 1024; idx += 256) {
        int r = idx >> 10, k = idx & 1023;
        int g = r >> 3, u = r & 7;
        Wl[k * 24 + r] = W0[(size_t)(g * 1024 + j0 + u) * 1024 + k];
    }
    const int b = tid & 7;
    const int kc = tid >> 3;      // 0..31
    const int kb = kc * 32;
    float* hb = hbuf + dir * 16384;
    int* cntp = flags + dir * 32;     // monotonic counter, own cache line per dir
    float bhh_r = 0.f;
    if (tid < 192) {
        int r = tid >> 3;
        int g = r >> 3, u = r & 7;
        bhh_r = bhh[dir * G3H + g * 1024 + j0 + u];
    }
    const float4* wbase[6];
    int qrow[6];
#pragma unroll
    for (int m = 0; m < 6; ++m) {
        int q = (m + kc) % 6;
        qrow[m] = q * 4;
        wbase[m] = (const float4*)&Wl[kb * 24 + q * 4];
    }
    __syncthreads();

    for (int s = 1; s <= 1024; ++s) {
        const int te = dir ? (1024 - s) : (s - 1);
        float xr = 0.f, xz = 0.f, xn = 0.f;
        if (tid < 64) {
            int u = tid >> 3, bb2 = tid & 7;
            const float* xp = xg + (size_t)(bb2 * 1024 + te) * 6144 + dir * G3H + j0 + u;
            xr = xp[0];
            xz = xp[1024];
            xn = xp[2048];
        }
        if (s > 1) {
            const int tgt = (s - 1) << 7;   // 128 * (s-1)
            int it = 0;
            while (__hip_atomic_load(cntp, __ATOMIC_RELAXED, __HIP_MEMORY_SCOPE_AGENT) < tgt) {
                if (++it > (1 << 22)) break;   // hang-guard only
                __builtin_amdgcn_s_sleep(1);
            }
        }
        const float* hp = hb + ((s - 1) & 1) * 8192;  // [k][b]
        float hreg[32];
#pragma unroll
        for (int i = 0; i < 32; ++i)
            hreg[i] = __hip_atomic_load(hp + (kb + i) * 8 + b,
                                        __ATOMIC_RELAXED, __HIP_MEMORY_SCOPE_AGENT);
        float hpg = 0.f;
        if (tid < 64)
            hpg = __hip_atomic_load(hp + (j0 + (tid >> 3)) * 8 + (tid & 7),
                                    __ATOMIC_RELAXED, __HIP_MEMORY_SCOPE_AGENT);

        float4 acc[6];
#pragma unroll
        for (int m = 0; m < 6; ++m) acc[m] = make_float4(0.f, 0.f, 0.f, 0.f);
#pragma unroll
        for (int i = 0; i < 32; ++i) {
            float hv = hreg[i];
#pragma unroll
            for (int m = 0; m < 6; ++m) {
                float4 wv = wbase[m][i * 6];
                acc[m].x = fmaf(wv.x, hv, acc[m].x);
                acc[m].y = fmaf(wv.y, hv, acc[m].y);
                acc[m].z = fmaf(wv.z, hv, acc[m].z);
                acc[m].w = fmaf(wv.w, hv, acc[m].w);
            }
        }
#pragma unroll
        for (int m = 0; m < 6; ++m) {
            float* rp = &red[kc * 200 + qrow[m] * 8 + b];
            rp[0] = acc[m].x;
            rp[8] = acc[m].y;
            rp[16] = acc[m].z;
            rp[24] = acc[m].w;
        }
        __syncthreads();
        if (tid < 192) {
            float sum = 0.f;
#pragma unroll
            for (int kk = 0; kk < 32; ++kk) sum += red[kk * 200 + tid];
            s2[tid] = sum + bhh_r;
        }
        __syncthreads();
        if (tid < 64) {
            int u = tid >> 3, bb2 = tid & 7;
            float hr = s2[u * 8 + bb2];
            float hz = s2[(8 + u) * 8 + bb2];
            float hn = s2[(16 + u) * 8 + bb2];
            float rg = 1.f / (1.f + expf(-(xr + hr)));
            float zg = 1.f / (1.f + expf(-(xz + hz)));
            float ng = tanhf(xn + rg * hn);
            float hnew = (1.f - zg) * ng + zg * hpg;
            __hip_atomic_store(hb + (s & 1) * 8192 + (j0 + u) * 8 + bb2, hnew,
                               __ATOMIC_RELAXED, __HIP_MEMORY_SCOPE_AGENT);
            float lr = hnew > 0.f ? hnew : 0.01f * hnew;
            flat[(size_t)(bb2 * 1024 + te) * 2048 + dir * 1024 + j0 + u] = lr;
        }
        if (tid < 64) {
            // wave 0 only: drain our coherent h stores, then post arrival
            __builtin_amdgcn_s_waitcnt(0);
            if (tid == 0)
                __hip_atomic_fetch_add(cntp, 1, __ATOMIC_RELAXED, __HIP_MEMORY_SCOPE_AGENT);
        }
    }
}

// =====================================================================
// K3: gating — fp32 logits from fp32 flat, softmax, top-2, aux partials
// =====================================================================
__global__ __launch_bounds__(256) void k3_gate(
    const float* __restrict__ flat, const float* __restrict__ gate_W,
    const float* __restrict__ gate_b,
    int* __restrict__ tk_idx, float* __restrict__ tk_w,
    int* __restrict__ counts, float* __restrict__ fmeta) {
    __shared__ float gw[8 * 2048];
    __shared__ float bP[9];
    __shared__ int bC[8];
    const int tid = threadIdx.x;
    for (int i = tid; i < 8 * 2048; i += 256) gw[i] = gate_W[i];
    if (tid < 9) bP[tid] = 0.f;
    if (tid < 8) bC[tid] = 0;
    __syncthreads();
    const int lane = tid & 63, w = tid >> 6;
    const int tbase = blockIdx.x * 16 + w * 4;
    for (int j = 0; j < 4; ++j) {
        int t = tbase + j;
        const float* fr = flat + (size_t)t * 2048;
        float a[8];
#pragma unroll
        for (int e = 0; e < 8; ++e) a[e] = 0.f;
        for (int i = 0; i < 32; ++i) {
            float v = fr[i * 64 + lane];
#pragma unroll
            for (int e = 0; e < 8; ++e) a[e] = fmaf(v, gw[e * 2048 + i * 64 + lane], a[e]);
        }
#pragma unroll
        for (int e = 0; e < 8; ++e) {
#pragma unroll
            for (int off = 32; off > 0; off >>= 1) a[e] += __shfl_down(a[e], off);
        }
        if (lane == 0) {
            float lg[8];
#pragma unroll
            for (int e = 0; e < 8; ++e) lg[e] = a[e] + gate_b[e];
            float m = lg[0];
#pragma unroll
            for (int e = 1; e < 8; ++e) m = fmaxf(m, lg[e]);
            float sc[8], ssum = 0.f;
#pragma unroll
            for (int e = 0; e < 8; ++e) { sc[e] = expf(lg[e] - m); ssum += sc[e]; }
            float inv = 1.f / ssum;
#pragma unroll
            for (int e = 0; e < 8; ++e) sc[e] *= inv;
            float lse = m + logf(ssum);
            int i1 = 0; float s1 = sc[0];
#pragma unroll
            for (int e = 1; e < 8; ++e) if (sc[e] > s1) { s1 = sc[e]; i1 = e; }
            int i2 = (i1 == 0) ? 1 : 0; float s2v = sc[i2];
#pragma unroll
            for (int e = 0; e < 8; ++e) if (e != i1 && sc[e] > s2v) { s2v = sc[e]; i2 = e; }
            float wsum = s1 + s2v;
            tk_idx[2 * t] = i1; tk_idx[2 * t + 1] = i2;
            tk_w[2 * t] = s1 / wsum; tk_w[2 * t + 1] = s2v / wsum;
            atomicAdd(&bC[i1], 1);
            atomicAdd(&bC[i2], 1);
#pragma unroll
            for (int e = 0; e < 8; ++e) atomicAdd(&bP[e], sc[e]);
            atomicAdd(&bP[8], lse * lse);
        }
    }
    __syncthreads();
    if (tid < 8) {
        atomicAdd(&counts[tid], bC[tid]);
        atomicAdd(&fmeta[tid], bP[tid]);
    }
    if (tid == 8) atomicAdd(&fmeta[8], bP[8]);
}

// =====================================================================
// K4: schedule (offsets, tile table) + aux loss
// =====================================================================
__global__ void k4_sched(int* im, float* fm, float* aux_out) {
    int tid = threadIdx.x;
    if (tid < 136) { im[32 + tid] = -1; im[168 + tid] = 0; }
    __syncthreads();
    if (tid == 0) {
        int off = 0;
        for (int e = 0; e < 8; ++e) { im[16 + e] = off; im[8 + e] = off; off += im[e]; }
        im[24] = off;
        int T = 0;
        for (int e = 0; e < 8; ++e) {
            int c = im[e], o = im[16 + e];
            for (int i = 0; i < c; i += 128) { im[32 + T] = e; im[168 + T] = o + i; ++T; }
        }
        im[25] = T;
        float fP = 0.f;
        for (int e = 0; e < 8; ++e) fP += ((float)im[e] / 8192.f) * (fm[e] / 8192.f);
        *aux_out = 0.01f * 8.f * fP + 0.001f * (fm[8] / 8192.f);
    }
}

// =====================================================================
// K5: scatter tokens into per-expert pair lists (block-aggregated atomics)
// =====================================================================
__global__ __launch_bounds__(256) void k5_scatter(
    const int* __restrict__ tk_idx, const float* __restrict__ tk_w,
    int* __restrict__ im, int* __restrict__ pair_t,
    float* __restrict__ pair_w, int* __restrict__ slot) {
    __shared__ int cnt[8], base[8];
    const int tid = threadIdx.x;
    if (tid < 8) cnt[tid] = 0;
    __syncthreads();
    const int t = blockIdx.x * 256 + tid;
    const int e0 = tk_idx[2 * t], e1 = tk_idx[2 * t + 1];
    const int p0 = atomicAdd(&cnt[e0], 1);
    const int p1 = atomicAdd(&cnt[e1], 1);
    __syncthreads();
    if (tid < 8) base[tid] = atomicAdd(&im[8 + tid], cnt[tid]);
    __syncthreads();
    const int q0 = base[e0] + p0, q1 = base[e1] + p1;
    pair_t[q0] = t; pair_w[q0] = tk_w[2 * t];     slot[2 * t] = q0;
    pair_t[q1] = t; pair_w[q1] = tk_w[2 * t + 1]; slot[2 * t + 1] = q1;
}

// =====================================================================
// K6: grouped FFN1 — Hg[p][f] = gelu(flat[token(p)] @ W1[e] + b1[e])
// =====================================================================
__global__ __launch_bounds__(256, 2) void k6_ffn1(
    const float* __restrict__ flat, const float* __restrict__ W1,
    const float* __restrict__ b1, const int* __restrict__ im,
    const int* __restrict__ pair_t, float* __restrict__ Hg) {
    const int rt = blockIdx.x % 136;
    const int nt = blockIdx.x / 136;
    const int e = im[32 + rt];
    if (e < 0) return;
    const int pStart = im[168 + rt];
    const int pEnd = im[16 + e + 1];
    __shared__ float As[16 * 132];
    __shared__ float Bs[16 * 132];
    const int tid = threadIdx.x;
    const int tx = tid & 15, ty = tid >> 4;
    const int n0 = nt * 128;
    const float* Bb = W1 + (size_t)e * 2048 * 2048;
    const int arow = tid >> 2, ac4 = (tid & 3) * 4;
    const int bk = tid >> 4, bn = (tid & 15) * 8;
    int r0 = pStart + arow;       if (r0 > pEnd - 1) r0 = pEnd - 1;
    int r1 = pStart + 64 + arow;  if (r1 > pEnd - 1) r1 = pEnd - 1;
    const float* arp0 = flat + (size_t)pair_t[r0] * 2048;
    const float* arp1 = flat + (size_t)pair_t[r1] * 2048;
    float acc[8][8];
#pragma unroll
    for (int i = 0; i < 8; ++i)
#pragma unroll
        for (int j = 0; j < 8; ++j) acc[i][j] = 0.f;

    for (int k0 = 0; k0 < 2048; k0 += 16) {
        __syncthreads();
        {
            float4 va = *(const float4*)(arp0 + k0 + ac4);
            As[(ac4 + 0) * 132 + arow] = va.x;
            As[(ac4 + 1) * 132 + arow] = va.y;
            As[(ac4 + 2) * 132 + arow] = va.z;
            As[(ac4 + 3) * 132 + arow] = va.w;
            float4 vb = *(const float4*)(arp1 + k0 + ac4);
            As[(ac4 + 0) * 132 + 64 + arow] = vb.x;
            As[(ac4 + 1) * 132 + 64 + arow] = vb.y;
            As[(ac4 + 2) * 132 + 64 + arow] = vb.z;
            As[(ac4 + 3) * 132 + 64 + arow] = vb.w;
            float4 w0 = *(const float4*)(Bb + (size_t)(k0 + bk) * 2048 + n0 + bn);
            float4 w1 = *(const float4*)(Bb + (size_t)(k0 + bk) * 2048 + n0 + bn + 4);
            *(float4*)&Bs[bk * 132 + bn] = w0;
            *(float4*)&Bs[bk * 132 + bn + 4] = w1;
        }
        __syncthreads();
#pragma unroll
        for (int k = 0; k < 16; ++k) {
            float4 a0 = *(const float4*)&As[k * 132 + ty * 8];
            float4 a1 = *(const float4*)&As[k * 132 + ty * 8 + 4];
            float4 b0 = *(const float4*)&Bs[k * 132 + tx * 8];
            float4 b1v = *(const float4*)&Bs[k * 132 + tx * 8 + 4];
            float av[8] = {a0.x, a0.y, a0.z, a0.w, a1.x, a1.y, a1.z, a1.w};
            float bv[8] = {b0.x, b0.y, b0.z, b0.w, b1v.x, b1v.y, b1v.z, b1v.w};
#pragma unroll
            for (int i = 0; i < 8; ++i)
#pragma unroll
                for (int j = 0; j < 8; ++j) acc[i][j] = fmaf(av[i], bv[j], acc[i][j]);
        }
    }
    float4 c0 = *(const float4*)(b1 + (size_t)e * 2048 + n0 + tx * 8);
    float4 c1 = *(const float4*)(b1 + (size_t)e * 2048 + n0 + tx * 8 + 4);
    float bb[8] = {c0.x, c0.y, c0.z, c0.w, c1.x, c1.y, c1.z, c1.w};
#pragma unroll
    for (int i = 0; i < 8; ++i) {
        int p = pStart + ty * 8 + i;
        if (p < pEnd) {
            float* op = Hg + (size_t)p * 2048 + n0 + tx * 8;
            float o[8];
#pragma unroll
            for (int j = 0; j < 8; ++j) {
                float xv = acc[i][j] + bb[j];
                o[j] = 0.5f * xv * (1.f + erff(xv * 0.70710678118654752f));
            }
            *(float4*)op = make_float4(o[0], o[1], o[2], o[3]);
            *(float4*)(op + 4) = make_float4(o[4], o[5], o[6], o[7]);
        }
    }
}

// =====================================================================
// K7: grouped FFN2 — Og[p][d] = Hg[p] @ W2[e] + b2[e]
// =====================================================================
__global__ __launch_bounds__(256, 2) void k7_ffn2(
    const float* __restrict__ Hg, const float* __restrict__ W2,
    const float* __restrict__ b2, const int* __restrict__ im,
    float* __restrict__ Og) {
    const int rt = blockIdx.x % 136;
    const int nt = blockIdx.x / 136;
    const int e = im[32 + rt];
    if (e < 0) return;
    const int pStart = im[168 + rt];
    const int pEnd = im[16 + e + 1];
    __shared__ float As[16 * 132];
    __shared__ float Bs[16 * 132];
    const int tid = threadIdx.x;
    const int tx = tid & 15, ty = tid >> 4;
    const int n0 = nt * 128;
    const float* Bb = W2 + (size_t)e * 2048 * 512;
    const int arow = tid >> 2, ac4 = (tid & 3) * 4;
    const int bk = tid >> 4, bn = (tid & 15) * 8;
    int r0 = pStart + arow;       if (r0 > pEnd - 1) r0 = pEnd - 1;
    int r1 = pStart + 64 + arow;  if (r1 > pEnd - 1) r1 = pEnd - 1;
    const float* arp0 = Hg + (size_t)r0 * 2048;
    const float* arp1 = Hg + (size_t)r1 * 2048;
    float acc[8][8];
#pragma unroll
    for (int i = 0; i < 8; ++i)
#pragma unroll
        for (int j = 0; j < 8; ++j) acc[i][j] = 0.f;

    for (int k0 = 0; k0 < 2048; k0 += 16) {
        __syncthreads();
        {
            float4 va = *(const float4*)(arp0 + k0 + ac4);
            As[(ac4 + 0) * 132 + arow] = va.x;
            As[(ac4 + 1) * 132 + arow] = va.y;
            As[(ac4 + 2) * 132 + arow] = va.z;
            As[(ac4 + 3) * 132 + arow] = va.w;
            float4 vb = *(const float4*)(arp1 + k0 + ac4);
            As[(ac4 + 0) * 132 + 64 + arow] = vb.x;
            As[(ac4 + 1) * 132 + 64 + arow] = vb.y;
            As[(ac4 + 2) * 132 + 64 + arow] = vb.z;
            As[(ac4 + 3) * 132 + 64 + arow] = vb.w;
            float4 w0 = *(const float4*)(Bb + (size_t)(k0 + bk) * 512 + n0 + bn);
            float4 w1 = *(const float4*)(Bb + (size_t)(k0 + bk) * 512 + n0 + bn + 4);
            *(float4*)&Bs[bk * 132 + bn] = w0;
            *(float4*)&Bs[bk * 132 + bn + 4] = w1;
        }
        __syncthreads();
#pragma unroll
        for (int k = 0; k < 16; ++k) {
            float4 a0 = *(const float4*)&As[k * 132 + ty * 8];
            float4 a1 = *(const float4*)&As[k * 132 + ty * 8 + 4];
            float4 b0 = *(const float4*)&Bs[k * 132 + tx * 8];
            float4 b1v = *(const float4*)&Bs[k * 132 + tx * 8 + 4];
            float av[8] = {a0.x, a0.y, a0.z, a0.w, a1.x, a1.y, a1.z, a1.w};
            float bv[8] = {b0.x, b0.y, b0.z, b0.w, b1v.x, b1v.y, b1v.z, b1v.w};
#pragma unroll
            for (int i = 0; i < 8; ++i)
#pragma unroll
                for (int j = 0; j < 8; ++j) acc[i][j] = fmaf(av[i], bv[j], acc[i][j]);
        }
    }
    float4 c0 = *(const float4*)(b2 + (size_t)e * 512 + n0 + tx * 8);
    float4 c1 = *(const float4*)(b2 + (size_t)e * 512 + n0 + tx * 8 + 4);
    float bb[8] = {c0.x, c0.y, c0.z, c0.w, c1.x, c1.y, c1.z, c1.w};
#pragma unroll
    for (int i = 0; i < 8; ++i) {
        int p = pStart + ty * 8 + i;
        if (p < pEnd) {
            float* op = Og + (size_t)p * 512 + n0 + tx * 8;
            *(float4*)op = make_float4(acc[i][0] + bb[0], acc[i][1] + bb[1],
                                       acc[i][2] + bb[2], acc[i][3] + bb[3]);
            *(float4*)(op + 4) = make_float4(acc[i][4] + bb[4], acc[i][5] + bb[5],
                                             acc[i][6] + bb[6], acc[i][7] + bb[7]);
        }
    }
}

// =====================================================================
// K8: combine — out[t] = w0*Og[s0] + w1*Og[s1]
// =====================================================================
__global__ __launch_bounds__(256) void k8_comb(
    const float* __restrict__ Og, const int* __restrict__ slot,
    const float* __restrict__ pw, float* __restrict__ out) {
    const int i4 = blockIdx.x * 256 + threadIdx.x;   // < 1048576
    const int t = i4 >> 7;
    const int d = (i4 & 127) << 2;
    const int s0 = slot[2 * t], s1 = slot[2 * t + 1];
    const float w0 = pw[s0], w1 = pw[s1];
    float4 a = *(const float4*)(Og + (size_t)s0 * 512 + d);
    float4 b = *(const float4*)(Og + (size_t)s1 * 512 + d);
    float4 o = make_float4(w0 * a.x + w1 * b.x, w0 * a.y + w1 * b.y,
                           w0 * a.z + w1 * b.z, w0 * a.w + w1 * b.w);
    *(float4*)(out + (size_t)t * 512 + d) = o;
}

// =====================================================================
extern "C" void kernel_launch(void* const* d_in, const int* in_sizes, int n_in,
                              void* d_out, int out_size, void* d_ws, size_t ws_size,
                              hipStream_t stream) {
    (void)in_sizes; (void)n_in; (void)out_size; (void)ws_size;
    const float* x   = (const float*)d_in[0];
    const float* Wih = (const float*)d_in[1];
    const float* Whh = (const float*)d_in[2];
    const float* bih = (const float*)d_in[3];
    const float* bhh = (const float*)d_in[4];
    const float* gW  = (const float*)d_in[5];
    const float* gb  = (const float*)d_in[6];
    const float* W1  = (const float*)d_in[7];
    const float* b1  = (const float*)d_in[8];
    const float* W2  = (const float*)d_in[9];
    const float* b2  = (const float*)d_in[10];
    float* out = (float*)d_out;
    char* ws = (char*)d_ws;
    float* xg    = (float*)(ws + XG_OFF);
    float* Hg    = (float*)(ws + HG_OFF);
    float* Og    = (float*)(ws + OG_OFF);
    float* flat  = (float*)(ws + FLAT_OFF);
    float* hbuf  = (float*)(ws + HBUF_OFF);
    int*   flags = (int*)(ws + FLAGS_OFF);
    int*   im    = (int*)(ws + IMETA_OFF);
    float* fm    = (float*)(ws + FMETA_OFF);
    int*   tki   = (int*)(ws + TKIDX_OFF);
    float* tkw   = (float*)(ws + TKW_OFF);
    int*   prt   = (int*)(ws + PAIRT_OFF);
    float* prw   = (float*)(ws + PAIRW_OFF);
    int*   slt   = (int*)(ws + SLOT_OFF);

    hipLaunchKernelGGL(k0_init, dim3(138), dim3(256), 0, stream, (float*)(ws + HBUF_OFF));
    hipLaunchKernelGGL(k1_sgemm_bt, dim3(48, 64), dim3(256), 0, stream, x, Wih, bih, xg);
    hipLaunchKernelGGL(k2_gru, dim3(256), dim3(256), 0, stream, Whh, bhh, xg, flat, hbuf, flags);
    hipLaunchKernelGGL(k3_gate, dim3(512), dim3(256), 0, stream, flat, gW, gb, tki, tkw, im, fm);
    hipLaunchKernelGGL(k4_sched, dim3(1), dim3(256), 0, stream, im, fm, out + 4194304);
    hipLaunchKernelGGL(k5_scatter, dim3(32), dim3(256), 0, stream, tki, tkw, im, prt, prw, slt);
    hipLaunchKernelGGL(k6_ffn1, dim3(136 * 16), dim3(256), 0, stream, flat, W1, b1, im, prt, Hg);
    hipLaunchKernelGGL(k7_ffn2, dim3(136 * 4), dim3(256), 0, stream, Hg, W2, b2, im, Og);
    hipLaunchKernelGGL(k8_comb, dim3(4096), dim3(256), 0, stream, Og, slt, prw, out);
}

// Round 3
// 11519.884 us; speedup vs baseline: 3.1086x; 1.4006x over previous
//
#include <hip/hip_runtime.h>
#include <math.h>

// ---------------- problem constants ----------------
#define NTOK 8192            // B*T
#define DM   512
#define HID  1024            // per-direction hidden
#define G3H  3072            // 3*HID
#define GOUT 2048            // 2*HID (bidir concat)
#define FFND 2048
#define NEXP 8

// ---------------- ws layout (bytes) ----------------
#define XG_OFF    0ULL                 // fp32 [8192][6144] = 201326592
#define HG_OFF    0ULL                 // alias (after GRU): fp32 [16384][2048] = 134217728
#define OG_OFF    134217728ULL         // fp32 [16384][512] = 33554432 (inside xg region)
#define FLAT_OFF  201326592ULL         // fp32 [8192][2048] = 67108864
#define HBUF_OFF  268435456ULL         // fp32 [2][2][8192] = 131072
#define FLAGS_OFF 268566528ULL         // int flags[2][128] (per-WG step numbers)
#define IMETA_OFF 268567552ULL         // int meta, 4096
#define FMETA_OFF 268571648ULL         // float meta, 4096
#define TKIDX_OFF 268575744ULL         // int [16384]
#define TKW_OFF   268641280ULL         // float [16384]
#define PAIRT_OFF 268706816ULL         // int [16384]
#define PAIRW_OFF 268772352ULL         // float [16384]
#define SLOT_OFF  268837888ULL         // int [16384]
// imeta ints: [0..8) counts, [8..16) cursor, [16..25) offs, [25] Ttot,
//             [32..168) tileExp, [168..304) tileStart
// fmeta floats: [0..8) sumP, [8] zacc

// =====================================================================
// K0: zero hbuf + flags + meta (region [HBUF_OFF, TKIDX_OFF) = 35072 floats)
// =====================================================================
__global__ void k0_init(float* p) {
    int i = blockIdx.x * 256 + threadIdx.x;
    if (i < 35072) p[i] = 0.f;
}

// =====================================================================
// K1: fp32 SGEMM  C[M=8192][N=6144] = A[8192][512] * B[6144][512]^T + bias[N]
// =====================================================================
__global__ __launch_bounds__(256, 2) void k1_sgemm_bt(
    const float* __restrict__ A, const float* __restrict__ B,
    const float* __restrict__ bias, float* __restrict__ C) {
    __shared__ float As[16 * 132];
    __shared__ float Bs[16 * 132];
    const int tid = threadIdx.x;
    const int m0 = blockIdx.y * 128;
    const int n0 = blockIdx.x * 128;
    const int tx = tid & 15, ty = tid >> 4;
    const int arow = tid >> 2, ac4 = (tid & 3) * 4;
    float acc[8][8];
#pragma unroll
    for (int i = 0; i < 8; ++i)
#pragma unroll
        for (int j = 0; j < 8; ++j) acc[i][j] = 0.f;

    for (int k0 = 0; k0 < 512; k0 += 16) {
        __syncthreads();
#pragma unroll
        for (int r = 0; r < 2; ++r) {
            int row = r * 64 + arow;
            float4 va = *(const float4*)(A + (size_t)(m0 + row) * 512 + k0 + ac4);
            As[(ac4 + 0) * 132 + row] = va.x;
            As[(ac4 + 1) * 132 + row] = va.y;
            As[(ac4 + 2) * 132 + row] = va.z;
            As[(ac4 + 3) * 132 + row] = va.w;
            float4 vb = *(const float4*)(B + (size_t)(n0 + row) * 512 + k0 + ac4);
            Bs[(ac4 + 0) * 132 + row] = vb.x;
            Bs[(ac4 + 1) * 132 + row] = vb.y;
            Bs[(ac4 + 2) * 132 + row] = vb.z;
            Bs[(ac4 + 3) * 132 + row] = vb.w;
        }
        __syncthreads();
#pragma unroll
        for (int k = 0; k < 16; ++k) {
            float4 a0 = *(const float4*)&As[k * 132 + ty * 8];
            float4 a1 = *(const float4*)&As[k * 132 + ty * 8 + 4];
            float4 b0 = *(const float4*)&Bs[k * 132 + tx * 8];
            float4 b1 = *(const float4*)&Bs[k * 132 + tx * 8 + 4];
            float av[8] = {a0.x, a0.y, a0.z, a0.w, a1.x, a1.y, a1.z, a1.w};
            float bv[8] = {b0.x, b0.y, b0.z, b0.w, b1.x, b1.y, b1.z, b1.w};
#pragma unroll
            for (int i = 0; i < 8; ++i)
#pragma unroll
                for (int j = 0; j < 8; ++j) acc[i][j] = fmaf(av[i], bv[j], acc[i][j]);
        }
    }
    float4 c0 = *(const float4*)(bias + n0 + tx * 8);
    float4 c1 = *(const float4*)(bias + n0 + tx * 8 + 4);
    float bb[8] = {c0.x, c0.y, c0.z, c0.w, c1.x, c1.y, c1.z, c1.w};
#pragma unroll
    for (int i = 0; i < 8; ++i) {
        float* op = C + (size_t)(m0 + ty * 8 + i) * 6144 + n0 + tx * 8;
        float4 o0 = make_float4(acc[i][0] + bb[0], acc[i][1] + bb[1],
                                acc[i][2] + bb[2], acc[i][3] + bb[3]);
        float4 o1 = make_float4(acc[i][4] + bb[4], acc[i][5] + bb[5],
                                acc[i][6] + bb[6], acc[i][7] + bb[7]);
        *(float4*)op = o0;
        *(float4*)(op + 4) = o1;
    }
}

// =====================================================================
// K2: persistent bidirectional GRU. 256 WGs (dir = bid>>7, 8 units each).
// Whh fp32 in LDS; h double-buffered in global via fine-grained coherent
// relaxed atomics (no cache-maintenance fences, no RMW atomics).
// Arrival: per-WG flag store; consumers poll 128 flags wave-parallel.
// =====================================================================
__global__ __launch_bounds__(256) void k2_gru(
    const float* __restrict__ Whh, const float* __restrict__ bhh,
    const float* __restrict__ xg, float* __restrict__ flat,
    float* __restrict__ hbuf, int* __restrict__ flags) {
    __shared__ float Wl[1024 * 24];   // [k][r]  r = g*8+u
    __shared__ float red[32 * 200];   // [kc][r*8+b] stride 200
    __shared__ float s2[192];
    const int tid = threadIdx.x;
    const int dir = blockIdx.x >> 7;
    const int wg = blockIdx.x & 127;
    const int j0 = wg * 8;
    const float* W0 = Whh + (size_t)dir * G3H * HID;
    for (int idx = tid; idx < 24 * 1024; idx += 256) {
        int r = idx >> 10, k = idx & 1023;
        int g = r >> 3, u = r & 7;
        Wl[k * 24 + r] = W0[(size_t)(g * 1024 + j0 + u) * 1024 + k];
    }
    const int lane = tid & 63;
    const int b = tid & 7;
    const int kc = tid >> 3;      // 0..31
    const int kb = kc * 32;
    float* hb = hbuf + dir * 16384;
    int* fl = flags + dir * 128;
    float bhh_r = 0.f;
    if (tid < 192) {
        int r = tid >> 3;
        int g = r >> 3, u = r & 7;
        bhh_r = bhh[dir * G3H + g * 1024 + j0 + u];
    }
    const float4* wbase[6];
    int qrow[6];
#pragma unroll
    for (int m = 0; m < 6; ++m) {
        int q = (m + kc) % 6;
        qrow[m] = q * 4;
        wbase[m] = (const float4*)&Wl[kb * 24 + q * 4];
    }
    __syncthreads();

    for (int s = 1; s <= 1024; ++s) {
        const int te = dir ? (1024 - s) : (s - 1);
        float xr = 0.f, xz = 0.f, xn = 0.f;
        if (tid < 64) {
            int u = tid >> 3, bb2 = tid & 7;
            const float* xp = xg + (size_t)(bb2 * 1024 + te) * 6144 + dir * G3H + j0 + u;
            xr = xp[0];
            xz = xp[1024];
            xn = xp[2048];
        }
        if (s > 1) {
            const int c0 = s - 1;
            int it = 0;
            for (;;) {
                int f0 = __hip_atomic_load(fl + lane, __ATOMIC_RELAXED, __HIP_MEMORY_SCOPE_AGENT);
                int f1 = __hip_atomic_load(fl + 64 + lane, __ATOMIC_RELAXED, __HIP_MEMORY_SCOPE_AGENT);
                if (__all((f0 >= c0) && (f1 >= c0))) break;
                if (++it > (1 << 22)) break;   // hang-guard only
                __builtin_amdgcn_s_sleep(1);
            }
        }
        const float* hp = hb + ((s - 1) & 1) * 8192;  // [k][b]
        float hreg[32];
#pragma unroll
        for (int i = 0; i < 32; ++i)
            hreg[i] = __hip_atomic_load(hp + (kb + i) * 8 + b,
                                        __ATOMIC_RELAXED, __HIP_MEMORY_SCOPE_AGENT);
        float hpg = 0.f;
        if (tid < 64)
            hpg = __hip_atomic_load(hp + (j0 + (tid >> 3)) * 8 + (tid & 7),
                                    __ATOMIC_RELAXED, __HIP_MEMORY_SCOPE_AGENT);

        float4 acc[6];
#pragma unroll
        for (int m = 0; m < 6; ++m) acc[m] = make_float4(0.f, 0.f, 0.f, 0.f);
#pragma unroll
        for (int i = 0; i < 32; ++i) {
            float hv = hreg[i];
#pragma unroll
            for (int m = 0; m < 6; ++m) {
                float4 wv = wbase[m][i * 6];
                acc[m].x = fmaf(wv.x, hv, acc[m].x);
                acc[m].y = fmaf(wv.y, hv, acc[m].y);
                acc[m].z = fmaf(wv.z, hv, acc[m].z);
                acc[m].w = fmaf(wv.w, hv, acc[m].w);
            }
        }
#pragma unroll
        for (int m = 0; m < 6; ++m) {
            float* rp = &red[kc * 200 + qrow[m] * 8 + b];
            rp[0] = acc[m].x;
            rp[8] = acc[m].y;
            rp[16] = acc[m].z;
            rp[24] = acc[m].w;
        }
        __syncthreads();
        if (tid < 192) {
            float sum = 0.f;
#pragma unroll
            for (int kk = 0; kk < 32; ++kk) sum += red[kk * 200 + tid];
            s2[tid] = sum + bhh_r;
        }
        __syncthreads();
        float hnew = 0.f;
        int u = tid >> 3, bb2 = tid & 7;
        if (tid < 64) {
            float hr = s2[u * 8 + bb2];
            float hz = s2[(8 + u) * 8 + bb2];
            float hn = s2[(16 + u) * 8 + bb2];
            float rg = 1.f / (1.f + expf(-(xr + hr)));
            float zg = 1.f / (1.f + expf(-(xz + hz)));
            float ng = tanhf(xn + rg * hn);
            hnew = (1.f - zg) * ng + zg * hpg;
            // coherent h store first — the only thing consumers wait on
            __hip_atomic_store(hb + (s & 1) * 8192 + (j0 + u) * 8 + bb2, hnew,
                               __ATOMIC_RELAXED, __HIP_MEMORY_SCOPE_AGENT);
        }
        if (tid < 64) {
            // wave 0: drain h stores, post arrival flag (plain store, no RMW)
            __builtin_amdgcn_s_waitcnt(0);
            if (tid == 0)
                __hip_atomic_store(fl + wg, s, __ATOMIC_RELAXED, __HIP_MEMORY_SCOPE_AGENT);
            // flat store off the critical path (consumed only after kernel end)
            float lr = hnew > 0.f ? hnew : 0.01f * hnew;
            flat[(size_t)(bb2 * 1024 + te) * 2048 + dir * 1024 + j0 + u] = lr;
        }
    }
}

// =====================================================================
// K3: gating — fp32 logits from fp32 flat, softmax, top-2, aux partials
// =====================================================================
__global__ __launch_bounds__(256) void k3_gate(
    const float* __restrict__ flat, const float* __restrict__ gate_W,
    const float* __restrict__ gate_b,
    int* __restrict__ tk_idx, float* __restrict__ tk_w,
    int* __restrict__ counts, float* __restrict__ fmeta) {
    __shared__ float gw[8 * 2048];
    __shared__ float bP[9];
    __shared__ int bC[8];
    const int tid = threadIdx.x;
    for (int i = tid; i < 8 * 2048; i += 256) gw[i] = gate_W[i];
    if (tid < 9) bP[tid] = 0.f;
    if (tid < 8) bC[tid] = 0;
    __syncthreads();
    const int lane = tid & 63, w = tid >> 6;
    const int tbase = blockIdx.x * 16 + w * 4;
    for (int j = 0; j < 4; ++j) {
        int t = tbase + j;
        const float* fr = flat + (size_t)t * 2048;
        float a[8];
#pragma unroll
        for (int e = 0; e < 8; ++e) a[e] = 0.f;
        for (int i = 0; i < 32; ++i) {
            float v = fr[i * 64 + lane];
#pragma unroll
            for (int e = 0; e < 8; ++e) a[e] = fmaf(v, gw[e * 2048 + i * 64 + lane], a[e]);
        }
#pragma unroll
        for (int e = 0; e < 8; ++e) {
#pragma unroll
            for (int off = 32; off > 0; off >>= 1) a[e] += __shfl_down(a[e], off);
        }
        if (lane == 0) {
            float lg[8];
#pragma unroll
            for (int e = 0; e < 8; ++e) lg[e] = a[e] + gate_b[e];
            float m = lg[0];
#pragma unroll
            for (int e = 1; e < 8; ++e) m = fmaxf(m, lg[e]);
            float sc[8], ssum = 0.f;
#pragma unroll
            for (int e = 0; e < 8; ++e) { sc[e] = expf(lg[e] - m); ssum += sc[e]; }
            float inv = 1.f / ssum;
#pragma unroll
            for (int e = 0; e < 8; ++e) sc[e] *= inv;
            float lse = m + logf(ssum);
            int i1 = 0; float s1 = sc[0];
#pragma unroll
            for (int e = 1; e < 8; ++e) if (sc[e] > s1) { s1 = sc[e]; i1 = e; }
            int i2 = (i1 == 0) ? 1 : 0; float s2v = sc[i2];
#pragma unroll
            for (int e = 0; e < 8; ++e) if (e != i1 && sc[e] > s2v) { s2v = sc[e]; i2 = e; }
            float wsum = s1 + s2v;
            tk_idx[2 * t] = i1; tk_idx[2 * t + 1] = i2;
            tk_w[2 * t] = s1 / wsum; tk_w[2 * t + 1] = s2v / wsum;
            atomicAdd(&bC[i1], 1);
            atomicAdd(&bC[i2], 1);
#pragma unroll
            for (int e = 0; e < 8; ++e) atomicAdd(&bP[e], sc[e]);
            atomicAdd(&bP[8], lse * lse);
        }
    }
    __syncthreads();
    if (tid < 8) {
        atomicAdd(&counts[tid], bC[tid]);
        atomicAdd(&fmeta[tid], bP[tid]);
    }
    if (tid == 8) atomicAdd(&fmeta[8], bP[8]);
}

// =====================================================================
// K4: schedule (offsets, tile table) + aux loss
// =====================================================================
__global__ void k4_sched(int* im, float* fm, float* aux_out) {
    int tid = threadIdx.x;
    if (tid < 136) { im[32 + tid] = -1; im[168 + tid] = 0; }
    __syncthreads();
    if (tid == 0) {
        int off = 0;
        for (int e = 0; e < 8; ++e) { im[16 + e] = off; im[8 + e] = off; off += im[e]; }
        im[24] = off;
        int T = 0;
        for (int e = 0; e < 8; ++e) {
            int c = im[e], o = im[16 + e];
            for (int i = 0; i < c; i += 128) { im[32 + T] = e; im[168 + T] = o + i; ++T; }
        }
        im[25] = T;
        float fP = 0.f;
        for (int e = 0; e < 8; ++e) fP += ((float)im[e] / 8192.f) * (fm[e] / 8192.f);
        *aux_out = 0.01f * 8.f * fP + 0.001f * (fm[8] / 8192.f);
    }
}

// =====================================================================
// K5: scatter tokens into per-expert pair lists (block-aggregated atomics)
// =====================================================================
__global__ __launch_bounds__(256) void k5_scatter(
    const int* __restrict__ tk_idx, const float* __restrict__ tk_w,
    int* __restrict__ im, int* __restrict__ pair_t,
    float* __restrict__ pair_w, int* __restrict__ slot) {
    __shared__ int cnt[8], base[8];
    const int tid = threadIdx.x;
    if (tid < 8) cnt[tid] = 0;
    __syncthreads();
    const int t = blockIdx.x * 256 + tid;
    const int e0 = tk_idx[2 * t], e1 = tk_idx[2 * t + 1];
    const int p0 = atomicAdd(&cnt[e0], 1);
    const int p1 = atomicAdd(&cnt[e1], 1);
    __syncthreads();
    if (tid < 8) base[tid] = atomicAdd(&im[8 + tid], cnt[tid]);
    __syncthreads();
    const int q0 = base[e0] + p0, q1 = base[e1] + p1;
    pair_t[q0] = t; pair_w[q0] = tk_w[2 * t];     slot[2 * t] = q0;
    pair_t[q1] = t; pair_w[q1] = tk_w[2 * t + 1]; slot[2 * t + 1] = q1;
}

// =====================================================================
// K6: grouped FFN1 — Hg[p][f] = gelu(flat[token(p)] @ W1[e] + b1[e])
// =====================================================================
__global__ __launch_bounds__(256, 2) void k6_ffn1(
    const float* __restrict__ flat, const float* __restrict__ W1,
    const float* __restrict__ b1, const int* __restrict__ im,
    const int* __restrict__ pair_t, float* __restrict__ Hg) {
    const int rt = blockIdx.x % 136;
    const int nt = blockIdx.x / 136;
    const int e = im[32 + rt];
    if (e < 0) return;
    const int pStart = im[168 + rt];
    const int pEnd = im[16 + e + 1];
    __shared__ float As[16 * 132];
    __shared__ float Bs[16 * 132];
    const int tid = threadIdx.x;
    const int tx = tid & 15, ty = tid >> 4;
    const int n0 = nt * 128;
    const float* Bb = W1 + (size_t)e * 2048 * 2048;
    const int arow = tid >> 2, ac4 = (tid & 3) * 4;
    const int bk = tid >> 4, bn = (tid & 15) * 8;
    int r0 = pStart + arow;       if (r0 > pEnd - 1) r0 = pEnd - 1;
    int r1 = pStart + 64 + arow;  if (r1 > pEnd - 1) r1 = pEnd - 1;
    const float* arp0 = flat + (size_t)pair_t[r0] * 2048;
    const float* arp1 = flat + (size_t)pair_t[r1] * 2048;
    float acc[8][8];
#pragma unroll
    for (int i = 0; i < 8; ++i)
#pragma unroll
        for (int j = 0; j < 8; ++j) acc[i][j] = 0.f;

    for (int k0 = 0; k0 < 2048; k0 += 16) {
        __syncthreads();
        {
            float4 va = *(const float4*)(arp0 + k0 + ac4);
            As[(ac4 + 0) * 132 + arow] = va.x;
            As[(ac4 + 1) * 132 + arow] = va.y;
            As[(ac4 + 2) * 132 + arow] = va.z;
            As[(ac4 + 3) * 132 + arow] = va.w;
            float4 vb = *(const float4*)(arp1 + k0 + ac4);
            As[(ac4 + 0) * 132 + 64 + arow] = vb.x;
            As[(ac4 + 1) * 132 + 64 + arow] = vb.y;
            As[(ac4 + 2) * 132 + 64 + arow] = vb.z;
            As[(ac4 + 3) * 132 + 64 + arow] = vb.w;
            float4 w0 = *(const float4*)(Bb + (size_t)(k0 + bk) * 2048 + n0 + bn);
            float4 w1 = *(const float4*)(Bb + (size_t)(k0 + bk) * 2048 + n0 + bn + 4);
            *(float4*)&Bs[bk * 132 + bn] = w0;
            *(float4*)&Bs[bk * 132 + bn + 4] = w1;
        }
        __syncthreads();
#pragma unroll
        for (int k = 0; k < 16; ++k) {
            float4 a0 = *(const float4*)&As[k * 132 + ty * 8];
            float4 a1 = *(const float4*)&As[k * 132 + ty * 8 + 4];
            float4 b0 = *(const float4*)&Bs[k * 132 + tx * 8];
            float4 b1v = *(const float4*)&Bs[k * 132 + tx * 8 + 4];
            float av[8] = {a0.x, a0.y, a0.z, a0.w, a1.x, a1.y, a1.z, a1.w};
            float bv[8] = {b0.x, b0.y, b0.z, b0.w, b1v.x, b1v.y, b1v.z, b1v.w};
#pragma unroll
            for (int i = 0; i < 8; ++i)
#pragma unroll
                for (int j = 0; j < 8; ++j) acc[i][j] = fmaf(av[i], bv[j], acc[i][j]);
        }
    }
    float4 c0 = *(const float4*)(b1 + (size_t)e * 2048 + n0 + tx * 8);
    float4 c1 = *(const float4*)(b1 + (size_t)e * 2048 + n0 + tx * 8 + 4);
    float bb[8] = {c0.x, c0.y, c0.z, c0.w, c1.x, c1.y, c1.z, c1.w};
#pragma unroll
    for (int i = 0; i < 8; ++i) {
        int p = pStart + ty * 8 + i;
        if (p < pEnd) {
            float* op = Hg + (size_t)p * 2048 + n0 + tx * 8;
            float o[8];
#pragma unroll
            for (int j = 0; j < 8; ++j) {
                float xv = acc[i][j] + bb[j];
                o[j] = 0.5f * xv * (1.f + erff(xv * 0.70710678118654752f));
            }
            *(float4*)op = make_float4(o[0], o[1], o[2], o[3]);
            *(float4*)(op + 4) = make_float4(o[4], o[5], o[6], o[7]);
        }
    }
}

// =====================================================================
// K7: grouped FFN2 — Og[p][d] = Hg[p] @ W2[e] + b2[e]
// =====================================================================
__global__ __launch_bounds__(256, 2) void k7_ffn2(
    const float* __restrict__ Hg, const float* __restrict__ W2,
    const float* __restrict__ b2, const int* __restrict__ im,
    float* __restrict__ Og) {
    const int rt = blockIdx.x % 136;
    const int nt = blockIdx.x / 136;
    const int e = im[32 + rt];
    if (e < 0) return;
    const int pStart = im[168 + rt];
    const int pEnd = im[16 + e + 1];
    __shared__ float As[16 * 132];
    __shared__ float Bs[16 * 132];
    const int tid = threadIdx.x;
    const int tx = tid & 15, ty = tid >> 4;
    const int n0 = nt * 128;
    const float* Bb = W2 + (size_t)e * 2048 * 512;
    const int arow = tid >> 2, ac4 = (tid & 3) * 4;
    const int bk = tid >> 4, bn = (tid & 15) * 8;
    int r0 = pStart + arow;       if (r0 > pEnd - 1) r0 = pEnd - 1;
    int r1 = pStart + 64 + arow;  if (r1 > pEnd - 1) r1 = pEnd - 1;
    const float* arp0 = Hg + (size_t)r0 * 2048;
    const float* arp1 = Hg + (size_t)r1 * 2048;
    float acc[8][8];
#pragma unroll
    for (int i = 0; i < 8; ++i)
#pragma unroll
        for (int j = 0; j < 8; ++j) acc[i][j] = 0.f;

    for (int k0 = 0; k0 < 2048; k0 += 16) {
        __syncthreads();
        {
            float4 va = *(const float4*)(arp0 + k0 + ac4);
            As[(ac4 + 0) * 132 + arow] = va.x;
            As[(ac4 + 1) * 132 + arow] = va.y;
            As[(ac4 + 2) * 132 + arow] = va.z;
            As[(ac4 + 3) * 132 + arow] = va.w;
            float4 vb = *(const float4*)(arp1 + k0 + ac4);
            As[(ac4 + 0) * 132 + 64 + arow] = vb.x;
            As[(ac4 + 1) * 132 + 64 + arow] = vb.y;
            As[(ac4 + 2) * 132 + 64 + arow] = vb.z;
            As[(ac4 + 3) * 132 + 64 + arow] = vb.w;
            float4 w0 = *(const float4*)(Bb + (size_t)(k0 + bk) * 512 + n0 + bn);
            float4 w1 = *(const float4*)(Bb + (size_t)(k0 + bk) * 512 + n0 + bn + 4);
            *(float4*)&Bs[bk * 132 + bn] = w0;
            *(float4*)&Bs[bk * 132 + bn + 4] = w1;
        }
        __syncthreads();
#pragma unroll
        for (int k = 0; k < 16; ++k) {
            float4 a0 = *(const float4*)&As[k * 132 + ty * 8];
            float4 a1 = *(const float4*)&As[k * 132 + ty * 8 + 4];
            float4 b0 = *(const float4*)&Bs[k * 132 + tx * 8];
            float4 b1v = *(const float4*)&Bs[k * 132 + tx * 8 + 4];
            float av[8] = {a0.x, a0.y, a0.z, a0.w, a1.x, a1.y, a1.z, a1.w};
            float bv[8] = {b0.x, b0.y, b0.z, b0.w, b1v.x, b1v.y, b1v.z, b1v.w};
#pragma unroll
            for (int i = 0; i < 8; ++i)
#pragma unroll
                for (int j = 0; j < 8; ++j) acc[i][j] = fmaf(av[i], bv[j], acc[i][j]);
        }
    }
    float4 c0 = *(const float4*)(b2 + (size_t)e * 512 + n0 + tx * 8);
    float4 c1 = *(const float4*)(b2 + (size_t)e * 512 + n0 + tx * 8 + 4);
    float bb[8] = {c0.x, c0.y, c0.z, c0.w, c1.x, c1.y, c1.z, c1.w};
#pragma unroll
    for (int i = 0; i < 8; ++i) {
        int p = pStart + ty * 8 + i;
        if (p < pEnd) {
            float* op = Og + (size_t)p * 512 + n0 + tx * 8;
            *(float4*)op = make_float4(acc[i][0] + bb[0], acc[i][1] + bb[1],
                                       acc[i][2] + bb[2], acc[i][3] + bb[3]);
            *(float4*)(op + 4) = make_float4(acc[i][4] + bb[4], acc[i][5] + bb[5],
                                             acc[i][6] + bb[6], acc[i][7] + bb[7]);
        }
    }
}

// =====================================================================
// K8: combine — out[t] = w0*Og[s0] + w1*Og[s1]
// =====================================================================
__global__ __launch_bounds__(256) void k8_comb(
    const float* __restrict__ Og, const int* __restrict__ slot,
    const float* __restrict__ pw, float* __restrict__ out) {
    const int i4 = blockIdx.x * 256 + threadIdx.x;   // < 1048576
    const int t = i4 >> 7;
    const int d = (i4 & 127) << 2;
    const int s0 = slot[2 * t], s1 = slot[2 * t + 1];
    const float w0 = pw[s0], w1 = pw[s1];
    float4 a = *(const float4*)(Og + (size_t)s0 * 512 + d);
    float4 b = *(const float4*)(Og + (size_t)s1 * 512 + d);
    float4 o = make_float4(w0 * a.x + w1 * b.x, w0 * a.y + w1 * b.y,
                           w0 * a.z + w1 * b.z, w0 * a.w + w1 * b.w);
    *(float4*)(out + (size_t)t * 512 + d) = o;
}

// =====================================================================
extern "C" void kernel_launch(void* const* d_in, const int* in_sizes, int n_in,
                              void* d_out, int out_size, void* d_ws, size_t ws_size,
                              hipStream_t stream) {
    (void)in_sizes; (void)n_in; (void)out_size; (void)ws_size;
    const float* x   = (const float*)d_in[0];
    const float* Wih = (const float*)d_in[1];
    const float* Whh = (const float*)d_in[2];
    const float* bih = (const float*)d_in[3];
    const float* bhh = (const float*)d_in[4];
    const float* gW  = (const float*)d_in[5];
    const float* gb  = (const float*)d_in[6];
    const float* W1  = (const float*)d_in[7];
    const float* b1  = (const float*)d_in[8];
    const float* W2  = (const float*)d_in[9];
    const float* b2  = (const float*)d_in[10];
    float* out = (float*)d_out;
    char* ws = (char*)d_ws;
    float* xg    = (float*)(ws + XG_OFF);
    float* Hg    = (float*)(ws + HG_OFF);
    float* Og    = (float*)(ws + OG_OFF);
    float* flat  = (float*)(ws + FLAT_OFF);
    float* hbuf  = (float*)(ws + HBUF_OFF);
    int*   flags = (int*)(ws + FLAGS_OFF);
    int*   im    = (int*)(ws + IMETA_OFF);
    float* fm    = (float*)(ws + FMETA_OFF);
    int*   tki   = (int*)(ws + TKIDX_OFF);
    float* tkw   = (float*)(ws + TKW_OFF);
    int*   prt   = (int*)(ws + PAIRT_OFF);
    float* prw   = (float*)(ws + PAIRW_OFF);
    int*   slt   = (int*)(ws + SLOT_OFF);

    hipLaunchKernelGGL(k0_init, dim3(138), dim3(256), 0, stream, (float*)(ws + HBUF_OFF));
    hipLaunchKernelGGL(k1_sgemm_bt, dim3(48, 64), dim3(256), 0, stream, x, Wih, bih, xg);
    hipLaunchKernelGGL(k2_gru, dim3(256), dim3(256), 0, stream, Whh, bhh, xg, flat, hbuf, flags);
    hipLaunchKernelGGL(k3_gate, dim3(512), dim3(256), 0, stream, flat, gW, gb, tki, tkw, im, fm);
    hipLaunchKernelGGL(k4_sched, dim3(1), dim3(256), 0, stream, im, fm, out + 4194304);
    hipLaunchKernelGGL(k5_scatter, dim3(32), dim3(256), 0, stream, tki, tkw, im, prt, prw, slt);
    hipLaunchKernelGGL(k6_ffn1, dim3(136 * 16), dim3(256), 0, stream, flat, W1, b1, im, prt, Hg);
    hipLaunchKernelGGL(k7_ffn2, dim3(136 * 4), dim3(256), 0, stream, Hg, W2, b2, im, Og);
    hipLaunchKernelGGL(k8_comb, dim3(4096), dim3(256), 0, stream, Og, slt, prw, out);
}